// Round 1
// baseline (576.169 us; speedup 1.0000x reference)
//
#include <hip/hip_runtime.h>
#include <hip/hip_fp16.h>

typedef _Float16 half8 __attribute__((ext_vector_type(8)));
typedef float f32x4 __attribute__((ext_vector_type(4)));

__device__ __forceinline__ float tanh_fast(float x) {
  float e = __expf(2.0f * x);
  return 1.0f - 2.0f / (e + 1.0f);
}

__device__ __forceinline__ void gload16(const _Float16* g, _Float16* l) {
  __builtin_amdgcn_global_load_lds((const __attribute__((address_space(1))) void*)g,
                                   (__attribute__((address_space(3))) void*)l,
                                   16, 0, 0);
}

// ---------------- transpose input_v [64][2048][196] f32 -> Vt [64][196][2048] fp16
__global__ __launch_bounds__(256) void k_transpose_v(const float* __restrict__ in,
                                                     _Float16* __restrict__ out) {
  __shared__ float t[32][33];
  int b = blockIdx.z;
  int p0 = blockIdx.x * 32;
  int c0 = blockIdx.y * 32;
  int tx = threadIdx.x;  // 0..31
  int ty = threadIdx.y;  // 0..7
  #pragma unroll
  for (int i = ty; i < 32; i += 8) {
    int p = p0 + tx;
    t[i][tx] = (p < 196) ? in[((size_t)b * 2048 + (c0 + i)) * 196 + p] : 0.0f;
  }
  __syncthreads();
  #pragma unroll
  for (int i = ty; i < 32; i += 8) {
    int p = p0 + i;
    if (p < 196) out[((size_t)b * 196 + p) * 2048 + (c0 + tx)] = (_Float16)t[tx][i];
  }
}

// ---------------- Wv_att [1200][2048] f32 -> fp16, zero-padded to 1280 rows
__global__ __launch_bounds__(256) void k_conv_w(const float* __restrict__ W,
                                                _Float16* __restrict__ Wh) {
  int i = blockIdx.x * 256 + threadIdx.x;  // < 1280*2048
  int n = i >> 11;
  Wh[i] = (n < 1200) ? (_Float16)W[i] : (_Float16)0.0f;
}

// ---------------- big MFMA GEMM + fused tanh/xq/tanh epilogue
// A: Vt [12544][2048] fp16 ; B: Wh [1280][2048] fp16 (row n = output col)
// xatt[row][col] = tanh( tanh(A.B^T + bv_att[col]) * xq[row/196][col] )
__global__ __launch_bounds__(256) void k_gemm1(const _Float16* __restrict__ A,
                                               const _Float16* __restrict__ B,
                                               const float* __restrict__ bias,
                                               const float* __restrict__ xq,
                                               _Float16* __restrict__ xatt) {
  __shared__ __align__(16) _Float16 As[128 * 32];
  __shared__ __align__(16) _Float16 Bs[128 * 32];
  int tid = threadIdx.x;
  int m0 = blockIdx.x * 128;  // 98 tiles, exact
  int n0 = blockIdx.y * 128;  // 10 tiles over padded 1280
  int lane = tid & 63;
  int wave = tid >> 6;
  int wm = (wave >> 1) * 64;
  int wn = (wave & 1) * 64;
  int fr = lane & 15;
  int fq = lane >> 4;

  int rowA = tid >> 2;        // 0..63
  int kp = (tid & 3) * 8;     // k sub-offset (halfs)
  const _Float16* aSrc0 = A + (size_t)(m0 + rowA) * 2048 + kp;
  const _Float16* aSrc1 = aSrc0 + (size_t)64 * 2048;
  const _Float16* bSrc0 = B + (size_t)(n0 + rowA) * 2048 + kp;
  const _Float16* bSrc1 = bSrc0 + (size_t)64 * 2048;
  _Float16* aDst0 = As + (wave * 64) * 8;
  _Float16* aDst1 = As + (256 + wave * 64) * 8;
  _Float16* bDst0 = Bs + (wave * 64) * 8;
  _Float16* bDst1 = Bs + (256 + wave * 64) * 8;

  f32x4 acc[4][4];
  #pragma unroll
  for (int i = 0; i < 4; ++i)
    #pragma unroll
    for (int j = 0; j < 4; ++j) acc[i][j] = (f32x4){0.f, 0.f, 0.f, 0.f};

  for (int kt = 0; kt < 64; ++kt) {
    int k0 = kt * 32;
    __syncthreads();
    gload16(aSrc0 + k0, aDst0);
    gload16(aSrc1 + k0, aDst1);
    gload16(bSrc0 + k0, bDst0);
    gload16(bSrc1 + k0, bDst1);
    __syncthreads();
    half8 af[4], bf[4];
    #pragma unroll
    for (int mt = 0; mt < 4; ++mt)
      af[mt] = *(const half8*)(As + (wm + mt * 16 + fr) * 32 + fq * 8);
    #pragma unroll
    for (int nt = 0; nt < 4; ++nt)
      bf[nt] = *(const half8*)(Bs + (wn + nt * 16 + fr) * 32 + fq * 8);
    #pragma unroll
    for (int mt = 0; mt < 4; ++mt)
      #pragma unroll
      for (int nt = 0; nt < 4; ++nt)
        acc[mt][nt] = __builtin_amdgcn_mfma_f32_16x16x32_f16(af[mt], bf[nt], acc[mt][nt], 0, 0, 0);
  }

  #pragma unroll
  for (int mt = 0; mt < 4; ++mt) {
    #pragma unroll
    for (int nt = 0; nt < 4; ++nt) {
      int col = n0 + wn + nt * 16 + fr;
      if (col < 1200) {
        float bcol = bias[col];
        #pragma unroll
        for (int r = 0; r < 4; ++r) {
          int row = m0 + wm + mt * 16 + fq * 4 + r;
          int b = row / 196;
          float xv = tanh_fast(acc[mt][nt][r] + bcol);
          float xa = tanh_fast(xv * xq[b * 1200 + col]);
          xatt[(size_t)row * 1200 + col] = (_Float16)xa;
        }
      }
    }
  }
}

// ---------------- wgt[b,g,p] = sum_d xatt[row][d]*Watt[g][d] + batt[g]
__global__ __launch_bounds__(256) void k_wgt(const _Float16* __restrict__ xatt,
                                             const float* __restrict__ Watt,
                                             const float* __restrict__ batt,
                                             float* __restrict__ wgt) {
  int row = blockIdx.x * 4 + (threadIdx.x >> 6);  // 12544 rows
  int lane = threadIdx.x & 63;
  const _Float16* xr = xatt + (size_t)row * 1200;
  float a0 = 0.f, a1 = 0.f;
  for (int d = lane; d < 1200; d += 64) {
    float x = (float)xr[d];
    a0 += x * Watt[d];
    a1 += x * Watt[1200 + d];
  }
  #pragma unroll
  for (int off = 32; off > 0; off >>= 1) {
    a0 += __shfl_down(a0, off);
    a1 += __shfl_down(a1, off);
  }
  if (lane == 0) {
    int b = row / 196, p = row % 196;
    wgt[((size_t)b * 2 + 0) * 196 + p] = a0 + batt[0];
    wgt[((size_t)b * 2 + 1) * 196 + p] = a1 + batt[1];
  }
}

// ---------------- softmax over 196 per (b,g); one wave per row
__global__ __launch_bounds__(64) void k_softmax(const float* __restrict__ wgt,
                                                float* __restrict__ att) {
  int bg = blockIdx.x;  // 128
  int lane = threadIdx.x;
  const float* wr = wgt + (size_t)bg * 196;
  float v[4];
  #pragma unroll
  for (int i = 0; i < 4; ++i) {
    int n = lane + i * 64;
    v[i] = (n < 196) ? wr[n] : -1e30f;
  }
  float mx = fmaxf(fmaxf(v[0], v[1]), fmaxf(v[2], v[3]));
  #pragma unroll
  for (int off = 32; off > 0; off >>= 1) mx = fmaxf(mx, __shfl_xor(mx, off));
  float s = 0.f;
  #pragma unroll
  for (int i = 0; i < 4; ++i) {
    int n = lane + i * 64;
    float e = (n < 196) ? __expf(v[i] - mx) : 0.f;
    v[i] = e;
    s += e;
  }
  #pragma unroll
  for (int off = 32; off > 0; off >>= 1) s += __shfl_xor(s, off);
  float inv = 1.f / s;
  #pragma unroll
  for (int i = 0; i < 4; ++i) {
    int n = lane + i * 64;
    if (n < 196) att[(size_t)bg * 196 + n] = v[i] * inv;
  }
}

// ---------------- v_att[b,g,d] = sum_n att[b,g,n] * Vt[b,n,d]
__global__ __launch_bounds__(256) void k_vatt(const _Float16* __restrict__ Vt,
                                              const float* __restrict__ att,
                                              float* __restrict__ v_att) {
  __shared__ float a0s[196], a1s[196];
  int b = blockIdx.y;
  int tid = threadIdx.x;
  if (tid < 196) {
    a0s[tid] = att[((size_t)b * 2 + 0) * 196 + tid];
    a1s[tid] = att[((size_t)b * 2 + 1) * 196 + tid];
  }
  __syncthreads();
  int d = blockIdx.x * 256 + tid;
  const _Float16* vp = Vt + (size_t)b * 196 * 2048 + d;
  float s0 = 0.f, s1 = 0.f;
  for (int n = 0; n < 196; ++n) {
    float v = (float)vp[(size_t)n * 2048];
    s0 += a0s[n] * v;
    s1 += a1s[n] * v;
  }
  v_att[((size_t)b * 2 + 0) * 2048 + d] = s0;
  v_att[((size_t)b * 2 + 1) * 2048 + d] = s1;
}

// ---------------- generic skinny GEMM, M=64, split-K partials
// P[s][m][z*colOffZ + n] = sum_{k in chunk s} A[m][k] (*A2[m][k]) * W[z][n][k]
__global__ __launch_bounds__(256) void k_skinny(const float* __restrict__ A1,
                                                const float* __restrict__ A2,
                                                int lda, int strideAz,
                                                const float* __restrict__ W, long strideWz,
                                                int N, int K, int S,
                                                float* __restrict__ P, int ldp, int colOffZ) {
  __shared__ __align__(16) float As[32][64];
  __shared__ __align__(16) float Ws2[32][64];
  int tid = threadIdx.x;
  int z = blockIdx.z;
  int s = blockIdx.y;
  int nt0 = blockIdx.x * 64;
  int tiles = K >> 5;
  int t0 = (s * tiles) / S;
  int t1 = ((s + 1) * tiles) / S;
  int tx = tid & 15, ty = tid >> 4;
  int lm = tid >> 2;
  int lk = (tid & 3) * 8;
  const float* Ab = A1 + (size_t)z * strideAz + (size_t)lm * lda;
  const float* A2b = A2 ? (A2 + (size_t)z * strideAz + (size_t)lm * lda) : nullptr;
  int ng = nt0 + lm;
  const float* Wb = W + (size_t)z * strideWz + (size_t)ng * K;
  bool wok = ng < N;
  float acc[4][4] = {};
  for (int t = t0; t < t1; ++t) {
    int k0 = t * 32;
    __syncthreads();
    #pragma unroll
    for (int j = 0; j < 8; ++j) {
      float v = Ab[k0 + lk + j];
      if (A2b) v *= A2b[k0 + lk + j];
      As[lk + j][lm] = v;
    }
    #pragma unroll
    for (int j = 0; j < 8; ++j) Ws2[lk + j][lm] = wok ? Wb[k0 + lk + j] : 0.0f;
    __syncthreads();
    #pragma unroll
    for (int kk = 0; kk < 32; ++kk) {
      f32x4 a = *(const f32x4*)&As[kk][ty * 4];
      f32x4 w = *(const f32x4*)&Ws2[kk][tx * 4];
      #pragma unroll
      for (int i = 0; i < 4; ++i)
        #pragma unroll
        for (int j = 0; j < 4; ++j) acc[i][j] += a[i] * w[j];
    }
  }
  #pragma unroll
  for (int i = 0; i < 4; ++i) {
    int m = ty * 4 + i;
    #pragma unroll
    for (int j = 0; j < 4; ++j) {
      int nl = nt0 + tx * 4 + j;
      if (nl < N) P[((size_t)s * 64 + m) * ldp + z * colOffZ + nl] = acc[i][j];
    }
  }
}

// ---------------- combine partials: out[i] = act(sum_s P[s][i] + bias[i%ldp])
__global__ __launch_bounds__(256) void k_combine(const float* __restrict__ P, int S, int ldp,
                                                 const float* __restrict__ bias,
                                                 float* __restrict__ out, int total, int act) {
  int i = blockIdx.x * 256 + threadIdx.x;
  if (i >= total) return;
  int col = i % ldp;
  float sum = bias[col];
  for (int ss = 0; ss < S; ++ss) sum += P[(size_t)ss * total + i];
  out[i] = act ? tanh_fast(sum) : sum;
}

extern "C" void kernel_launch(void* const* d_in, const int* in_sizes, int n_in,
                              void* d_out, int out_size, void* d_ws, size_t ws_size,
                              hipStream_t stream) {
  const float* input_q = (const float*)d_in[0];
  const float* input_v = (const float*)d_in[1];
  const float* Wv_att  = (const float*)d_in[2];
  const float* bv_att  = (const float*)d_in[3];
  const float* Wq_att  = (const float*)d_in[4];
  const float* bq_att  = (const float*)d_in[5];
  const float* Watt    = (const float*)d_in[6];
  const float* batt    = (const float*)d_in[7];
  const float* Wv_fus  = (const float*)d_in[8];
  const float* bv_fus  = (const float*)d_in[9];
  const float* Wq_fus  = (const float*)d_in[10];
  const float* bq_fus  = (const float*)d_in[11];
  const float* Wc      = (const float*)d_in[12];
  const float* bc      = (const float*)d_in[13];
  float* out = (float*)d_out;

  char* ws = (char*)d_ws;
  _Float16* Vt   = (_Float16*)ws; ws += 51380224;   // 64*196*2048 fp16
  _Float16* Wh   = (_Float16*)ws; ws += 5242880;    // 1280*2048 fp16
  float* xq      = (float*)ws;    ws += 307200;     // 64*1200 f32
  _Float16* xatt = (_Float16*)ws; ws += 30105600;   // 12544*1200 fp16
  float* att     = (float*)ws;    ws += 100352;     // 64*2*196 f32
  float* v_att   = (float*)ws;    ws += 1048576;    // 64*2*2048 f32
  float* v_fus   = (float*)ws;    ws += 614400;     // 64*2400 f32
  float* q_fus   = (float*)ws;    ws += 614400;     // 64*2400 f32
  float* P       = (float*)ws;    ws += 6144000;    // 8*64*3000 f32

  float* x_out   = out;            // [64][3000]
  float* wgt_out = out + 192000;   // [64][2][196]

  const int S = 8;

  // stage conversions
  k_transpose_v<<<dim3(7, 64, 64), dim3(32, 8), 0, stream>>>(input_v, Vt);
  k_conv_w<<<dim3(10240), dim3(256), 0, stream>>>(Wv_att, Wh);

  // xq = tanh(input_q @ Wq_att^T + bq_att)
  k_skinny<<<dim3(19, S, 1), dim3(256), 0, stream>>>(input_q, nullptr, 2400, 0,
                                                     Wq_att, 0, 1200, 2400, S, P, 1200, 0);
  k_combine<<<dim3(300), dim3(256), 0, stream>>>(P, S, 1200, bq_att, xq, 76800, 1);

  // xatt = tanh(tanh(V.Wv^T + bv) * xq)
  k_gemm1<<<dim3(98, 10), dim3(256), 0, stream>>>(Vt, Wh, bv_att, xq, xatt);

  // wgt (output 1) + softmax -> att
  k_wgt<<<dim3(3136), dim3(256), 0, stream>>>(xatt, Watt, batt, wgt_out);
  k_softmax<<<dim3(128), dim3(64), 0, stream>>>(wgt_out, att);

  // v_att
  k_vatt<<<dim3(8, 64), dim3(256), 0, stream>>>(Vt, att, v_att);

  // v_fus = tanh(v_att @ Wv_fus^T + bv_fus)  (z=0,1 -> cols 0..1199 / 1200..2399)
  k_skinny<<<dim3(19, S, 2), dim3(256), 0, stream>>>(v_att, nullptr, 4096, 2048,
                                                     Wv_fus, 1200L * 2048L, 1200, 2048, S, P, 2400, 1200);
  k_combine<<<dim3(600), dim3(256), 0, stream>>>(P, S, 2400, bv_fus, v_fus, 153600, 1);

  // q_fus = tanh(input_q @ Wq_fus^T + bq_fus)
  k_skinny<<<dim3(38, S, 1), dim3(256), 0, stream>>>(input_q, nullptr, 2400, 0,
                                                     Wq_fus, 0, 2400, 2400, S, P, 2400, 0);
  k_combine<<<dim3(600), dim3(256), 0, stream>>>(P, S, 2400, bq_fus, q_fus, 153600, 1);

  // x = (v_fus * q_fus) @ Wc^T + bc  (output 0)
  k_skinny<<<dim3(47, S, 1), dim3(256), 0, stream>>>(v_fus, q_fus, 2400, 0,
                                                     Wc, 0, 3000, 2400, S, P, 3000, 0);
  k_combine<<<dim3(750), dim3(256), 0, stream>>>(P, S, 3000, bc, x_out, 192000, 0);
}